// Round 1
// baseline (824.655 us; speedup 1.0000x reference)
//
#include <hip/hip_runtime.h>
#include <hip/hip_bf16.h>

typedef __bf16 bf16_t;
typedef bf16_t bf16x8 __attribute__((ext_vector_type(8)));
typedef bf16_t bf16x4 __attribute__((ext_vector_type(4)));
typedef float f32x4 __attribute__((ext_vector_type(4)));

#define EPS_BN 1e-5f
#define EPS_LN 1e-5f

// ---------------- CSR build ----------------

__global__ void initK(float* __restrict__ deg, int* __restrict__ cnt, int n) {
    int i = blockIdx.x * 256 + threadIdx.x;
    if (i < n) { deg[i] = 1.0f; cnt[i] = 0; }   // self-loop weight 1
}

__global__ void edgeK(const int* __restrict__ ei, const float* __restrict__ ea,
                      float* __restrict__ deg, int* __restrict__ cnt, int E) {
    int e = blockIdx.x * 256 + threadIdx.x;
    if (e >= E) return;
    int d = ei[E + e];           // edge_index[1][e]
    atomicAdd(&deg[d], ea[e]);
    atomicAdd(&cnt[d], 1);
}

__global__ void scan1K(const int* __restrict__ cnt, int* __restrict__ excl,
                       int* __restrict__ bs, int n) {
    __shared__ int sd[256];
    int tid = threadIdx.x;
    int base = blockIdx.x * 1024 + tid * 4;
    int v0 = (base + 0 < n) ? cnt[base + 0] : 0;
    int v1 = (base + 1 < n) ? cnt[base + 1] : 0;
    int v2 = (base + 2 < n) ? cnt[base + 2] : 0;
    int v3 = (base + 3 < n) ? cnt[base + 3] : 0;
    int tsum = v0 + v1 + v2 + v3;
    sd[tid] = tsum; __syncthreads();
    for (int off = 1; off < 256; off <<= 1) {
        int t = (tid >= off) ? sd[tid - off] : 0;
        __syncthreads();
        sd[tid] += t;
        __syncthreads();
    }
    int ex = sd[tid] - tsum;
    if (tid == 255) bs[blockIdx.x] = sd[255];
    if (base + 0 < n) excl[base + 0] = ex;
    if (base + 1 < n) excl[base + 1] = ex + v0;
    if (base + 2 < n) excl[base + 2] = ex + v0 + v1;
    if (base + 3 < n) excl[base + 3] = ex + v0 + v1 + v2;
}

__global__ void scan2K(int* __restrict__ bs, int m) {
    __shared__ int sd[256];
    int tid = threadIdx.x;
    int v = (tid < m) ? bs[tid] : 0;
    sd[tid] = v; __syncthreads();
    for (int off = 1; off < 256; off <<= 1) {
        int t = (tid >= off) ? sd[tid - off] : 0;
        __syncthreads();
        sd[tid] += t;
        __syncthreads();
    }
    if (tid < m) bs[tid] = sd[tid] - v;   // exclusive block offsets, in place
}

__global__ void finalizeK(int* __restrict__ rowStart, const int* __restrict__ bs,
                          const float* __restrict__ deg, float* __restrict__ dinv,
                          int* __restrict__ cursor, int n) {
    int i = blockIdx.x * 256 + threadIdx.x;
    if (i >= n) return;
    int rs = rowStart[i] + bs[i >> 10];
    rowStart[i] = rs;
    cursor[i] = rs;
    float d = deg[i];
    dinv[i] = (d > 0.f) ? rsqrtf(fmaxf(d, 1e-12f)) : 0.f;
}

__global__ void fillK(const int* __restrict__ ei, const float* __restrict__ ea,
                      int* __restrict__ cursor, int* __restrict__ csrc,
                      float* __restrict__ cw, int E) {
    int e = blockIdx.x * 256 + threadIdx.x;
    if (e >= E) return;
    int d = ei[E + e];
    int pos = atomicAdd(&cursor[d], 1);
    csrc[pos] = ei[e];
    cw[pos] = ea[e];
}

// ---------------- weight convert: W[i][o] fp32 -> WT[o*136+i] bf16 (padded) ----------------

__global__ void convertWK(const float* __restrict__ W, bf16_t* __restrict__ WT) {
    int flat = blockIdx.x * 256 + threadIdx.x;   // 0..16383
    int i = flat >> 7, o = flat & 127;
    WT[o * 136 + i] = (bf16_t)W[flat];
}

// ---------------- GEMM: out[r][j] = epilogue( sum_k A[r][k]*W[k][j] ) ----------------
// MODE 0: BN(acc + colBias) then ReLU   (input preprocess)
// MODE 1: acc * dinv[row]               (pre-scaled conv message)
// MODE 2: acc + colBias                 (classifier linear 1)

template <int MODE>
__global__ __launch_bounds__(256) void gemm128K(
    const float* __restrict__ A, const bf16_t* __restrict__ WT,
    float* __restrict__ out,
    const float* __restrict__ colBias,
    const float* __restrict__ bnMean, const float* __restrict__ bnVar,
    const float* __restrict__ bnG, const float* __restrict__ bnB,
    const float* __restrict__ dinv, int nrows)
{
    __shared__ __align__(16) bf16_t As[64 * 136];
    __shared__ __align__(16) bf16_t Bs[128 * 136];
    int tid = threadIdx.x;
    int rb = blockIdx.x * 64;

    // stage WT (already padded, 128*136 bf16 = 34816 B) straight into LDS
    {
        const uint4* src = (const uint4*)WT;
        uint4* dst = (uint4*)Bs;
        for (int i = tid; i < (128 * 136 * 2) / 16; i += 256) dst[i] = src[i];
    }
    // stage A tile (64 rows x 128 cols fp32 -> bf16, padded stride 136)
    {
        for (int it = 0; it < 8; ++it) {
            int flat = it * 1024 + tid * 4;
            int r = flat >> 7, c = flat & 127;
            int row = rb + r;
            float4 v;
            if (row < nrows) v = ((const float4*)A)[(size_t)row * 32 + (c >> 2)];
            else             v = make_float4(0.f, 0.f, 0.f, 0.f);
            bf16x4 w4;
            w4.x = (bf16_t)v.x; w4.y = (bf16_t)v.y; w4.z = (bf16_t)v.z; w4.w = (bf16_t)v.w;
            *(bf16x4*)&As[r * 136 + c] = w4;
        }
    }
    __syncthreads();

    int lane = tid & 63;
    int wid = tid >> 6;
    int m = lane & 15, q = lane >> 4;

    f32x4 acc[8];
#pragma unroll
    for (int c = 0; c < 8; ++c) acc[c] = (f32x4){0.f, 0.f, 0.f, 0.f};

    const bf16_t* aRow = &As[(wid * 16 + m) * 136 + q * 8];
#pragma unroll
    for (int kk = 0; kk < 4; ++kk) {
        bf16x8 af = *(const bf16x8*)(aRow + kk * 32);
#pragma unroll
        for (int c = 0; c < 8; ++c) {
            bf16x8 bfr = *(const bf16x8*)&Bs[(c * 16 + m) * 136 + q * 8 + kk * 32];
            acc[c] = __builtin_amdgcn_mfma_f32_16x16x32_bf16(af, bfr, acc[c], 0, 0, 0);
        }
    }

    int r0 = rb + wid * 16 + q * 4;
    float dv[4];
    if (MODE == 1) {
#pragma unroll
        for (int i = 0; i < 4; ++i) dv[i] = (r0 + i < nrows) ? dinv[r0 + i] : 0.f;
    }
#pragma unroll
    for (int c = 0; c < 8; ++c) {
        int j = c * 16 + m;
        float cb = 0.f, scale = 1.f, shift = 0.f;
        if (MODE == 0) {
            cb = colBias[j];
            float rs = rsqrtf(bnVar[j] + EPS_BN);
            scale = bnG[j] * rs;
            shift = bnB[j] - bnMean[j] * scale;
        } else if (MODE == 2) {
            cb = colBias[j];
        }
#pragma unroll
        for (int i = 0; i < 4; ++i) {
            int r = r0 + i;
            if (r < nrows) {
                float v = acc[c][i];
                if (MODE == 0) { v = (v + cb) * scale + shift; v = fmaxf(v, 0.f); }
                else if (MODE == 1) { v = v * dv[i]; }
                else { v = v + cb; }
                out[(size_t)r * 128 + j] = v;
            }
        }
    }
}

// ---------------- aggregation: out[d] = act(dinv[d]*(ts[d] + sum w*ts[src]) + b (+res)) ----------------

__global__ __launch_bounds__(256) void aggK(
    const float* __restrict__ ts, const int* __restrict__ rowStart,
    const int* __restrict__ cnt, const int* __restrict__ csrc,
    const float* __restrict__ cw, const float* __restrict__ dinv,
    const float* __restrict__ bias, const float* __restrict__ residual,
    float* __restrict__ out, int n, int doRelu)
{
    int node = blockIdx.x * 4 + (threadIdx.x >> 6);
    int lane = threadIdx.x & 63;
    if (node >= n) return;
    const float2* tsv = (const float2*)ts;
    float2 acc = tsv[(size_t)node * 64 + lane];   // self-loop term
    int start = rowStart[node], count = cnt[node];
    for (int c0 = 0; c0 < count; c0 += 64) {
        int i = c0 + lane;
        int s = 0; float w = 0.f;
        if (i < count) { s = csrc[start + i]; w = cw[start + i]; }
        int mm = min(64, count - c0);
        for (int j = 0; j < mm; ++j) {
            int sj = __shfl(s, j);
            float wj = __shfl(w, j);
            float2 v = tsv[(size_t)sj * 64 + lane];
            acc.x += wj * v.x;
            acc.y += wj * v.y;
        }
    }
    float di = dinv[node];
    float2 bb = ((const float2*)bias)[lane];
    float rx = acc.x * di + bb.x;
    float ry = acc.y * di + bb.y;
    if (residual) {
        float2 rr = ((const float2*)residual)[(size_t)node * 64 + lane];
        rx += rr.x; ry += rr.y;
    }
    if (doRelu) { rx = fmaxf(rx, 0.f); ry = fmaxf(ry, 0.f); }
    ((float2*)out)[(size_t)node * 64 + lane] = make_float2(rx, ry);
}

// ---------------- final: LayerNorm -> ReLU -> Linear(128->3) ----------------

__global__ __launch_bounds__(256) void finalK(
    const float* __restrict__ Z, const float* __restrict__ g,
    const float* __restrict__ b, const float* __restrict__ Wc2,
    const float* __restrict__ bc2, float* __restrict__ out, int n)
{
    int node = blockIdx.x * 4 + (threadIdx.x >> 6);
    int lane = threadIdx.x & 63;
    if (node >= n) return;
    float2 z = ((const float2*)Z)[(size_t)node * 64 + lane];
    float s1 = z.x + z.y;
    float s2 = z.x * z.x + z.y * z.y;
    for (int off = 1; off < 64; off <<= 1) {
        s1 += __shfl_xor(s1, off);
        s2 += __shfl_xor(s2, off);
    }
    float mu = s1 * (1.f / 128.f);
    float var = s2 * (1.f / 128.f) - mu * mu;
    float rstd = rsqrtf(var + EPS_LN);
    float zx = fmaxf((z.x - mu) * rstd * g[2 * lane] + b[2 * lane], 0.f);
    float zy = fmaxf((z.y - mu) * rstd * g[2 * lane + 1] + b[2 * lane + 1], 0.f);
    float p0 = zx * Wc2[(2 * lane) * 3 + 0] + zy * Wc2[(2 * lane + 1) * 3 + 0];
    float p1 = zx * Wc2[(2 * lane) * 3 + 1] + zy * Wc2[(2 * lane + 1) * 3 + 1];
    float p2 = zx * Wc2[(2 * lane) * 3 + 2] + zy * Wc2[(2 * lane + 1) * 3 + 2];
    for (int off = 1; off < 64; off <<= 1) {
        p0 += __shfl_xor(p0, off);
        p1 += __shfl_xor(p1, off);
        p2 += __shfl_xor(p2, off);
    }
    if (lane == 0) {
        out[(size_t)node * 3 + 0] = p0 + bc2[0];
        out[(size_t)node * 3 + 1] = p1 + bc2[1];
        out[(size_t)node * 3 + 2] = p2 + bc2[2];
    }
}

// ---------------- launch ----------------

extern "C" void kernel_launch(void* const* d_in, const int* in_sizes, int n_in,
                              void* d_out, int out_size, void* d_ws, size_t ws_size,
                              hipStream_t stream) {
    const float* x      = (const float*)d_in[0];
    const int*   ei     = (const int*)d_in[1];
    const float* ea     = (const float*)d_in[2];
    const float* W_pre  = (const float*)d_in[3];
    const float* b_pre  = (const float*)d_in[4];
    const float* bn_g   = (const float*)d_in[5];
    const float* bn_b   = (const float*)d_in[6];
    const float* bn_m   = (const float*)d_in[7];
    const float* bn_v   = (const float*)d_in[8];
    const float* W1     = (const float*)d_in[9];
    const float* b1     = (const float*)d_in[10];
    const float* W2     = (const float*)d_in[11];
    const float* b2     = (const float*)d_in[12];
    const float* Wc1    = (const float*)d_in[13];
    const float* bc1    = (const float*)d_in[14];
    const float* ln_g   = (const float*)d_in[15];
    const float* ln_b   = (const float*)d_in[16];
    const float* Wc2    = (const float*)d_in[17];
    const float* bc2    = (const float*)d_in[18];
    float* outp = (float*)d_out;

    const int N = in_sizes[0] / 128;
    const int E = in_sizes[2];

    char* p = (char*)d_ws;
    auto alloc = [&](size_t bytes) -> void* {
        void* r = (void*)p;
        p += (bytes + 255) & ~(size_t)255;
        return r;
    };
    float* h0     = (float*)alloc((size_t)N * 128 * 4);
    float* bufA   = (float*)alloc((size_t)N * 128 * 4);
    float* bufB   = (float*)alloc((size_t)N * 128 * 4);
    float* deg    = (float*)alloc((size_t)N * 4);
    float* dinv   = (float*)alloc((size_t)N * 4);
    int*   cnt    = (int*)alloc((size_t)N * 4);
    int*   rowSt  = (int*)alloc((size_t)N * 4);
    int*   cursor = (int*)alloc((size_t)N * 4);
    int*   bs     = (int*)alloc(4096);
    int*   csrc   = (int*)alloc((size_t)E * 4);
    float* cw     = (float*)alloc((size_t)E * 4);
    bf16_t* WT    = (bf16_t*)alloc((size_t)4 * 128 * 136 * 2);

    bf16_t* WT_pre = WT + 0 * 128 * 136;
    bf16_t* WT_1   = WT + 1 * 128 * 136;
    bf16_t* WT_2   = WT + 2 * 128 * 136;
    bf16_t* WT_c1  = WT + 3 * 128 * 136;

    int gN = (N + 255) / 256;
    int gE = (E + 255) / 256;
    int nb1 = (N + 1023) / 1024;
    int gG = (N + 63) / 64;
    int gW = (N + 3) / 4;

    // CSR + dinv build
    initK<<<gN, 256, 0, stream>>>(deg, cnt, N);
    edgeK<<<gE, 256, 0, stream>>>(ei, ea, deg, cnt, E);
    scan1K<<<nb1, 256, 0, stream>>>(cnt, rowSt, bs, N);
    scan2K<<<1, 256, 0, stream>>>(bs, nb1);
    finalizeK<<<gN, 256, 0, stream>>>(rowSt, bs, deg, dinv, cursor, N);
    fillK<<<gE, 256, 0, stream>>>(ei, ea, cursor, csrc, cw, E);

    // weights -> bf16 transposed, padded
    convertWK<<<64, 256, 0, stream>>>(W_pre, WT_pre);
    convertWK<<<64, 256, 0, stream>>>(W1, WT_1);
    convertWK<<<64, 256, 0, stream>>>(W2, WT_2);
    convertWK<<<64, 256, 0, stream>>>(Wc1, WT_c1);

    // h0 = relu(bn(x@W_pre + b_pre))
    gemm128K<0><<<gG, 256, 0, stream>>>(x, WT_pre, h0, b_pre, bn_m, bn_v, bn_g, bn_b, nullptr, N);
    // conv1: ts1 = dinv * (h0@W1); h1 = relu(dinv*(ts1[d] + sum) + b1)
    gemm128K<1><<<gG, 256, 0, stream>>>(h0, WT_1, bufA, nullptr, nullptr, nullptr, nullptr, nullptr, dinv, N);
    aggK<<<gW, 256, 0, stream>>>(bufA, rowSt, cnt, csrc, cw, dinv, b1, nullptr, bufB, N, 1);
    // conv2: ts2 = dinv * (h1@W2); h = dinv*(...) + b2 + h0
    gemm128K<1><<<gG, 256, 0, stream>>>(bufB, WT_2, bufA, nullptr, nullptr, nullptr, nullptr, nullptr, dinv, N);
    aggK<<<gW, 256, 0, stream>>>(bufA, rowSt, cnt, csrc, cw, dinv, b2, h0, bufB, N, 0);
    // z = h@Wc1 + bc1
    gemm128K<2><<<gG, 256, 0, stream>>>(bufB, WT_c1, bufA, bc1, nullptr, nullptr, nullptr, nullptr, nullptr, N);
    // out = relu(LN(z)) @ Wc2 + bc2
    finalK<<<gW, 256, 0, stream>>>(bufA, ln_g, ln_b, Wc2, bc2, outp, N);
}

// Round 2
// 604.199 us; speedup vs baseline: 1.3649x; 1.3649x over previous
//
#include <hip/hip_runtime.h>
#include <hip/hip_bf16.h>

typedef __bf16 bf16_t;
typedef bf16_t bf16x8 __attribute__((ext_vector_type(8)));
typedef bf16_t bf16x4 __attribute__((ext_vector_type(4)));
typedef bf16_t bf16x2 __attribute__((ext_vector_type(2)));
typedef float f32x4 __attribute__((ext_vector_type(4)));

#define EPS_BN 1e-5f
#define EPS_LN 1e-5f
#define SLOTS 64

// ---------------- adjacency build: fixed 64 slots per dst node ----------------

__global__ void initK(int* __restrict__ cnt, int* __restrict__ ovCnt, int n) {
    int i = blockIdx.x * 256 + threadIdx.x;
    if (i < n) cnt[i] = 0;
    if (i == 0) *ovCnt = 0;
}

__global__ __launch_bounds__(256) void fillSlotsK(
    const int* __restrict__ ei, const float* __restrict__ ea,
    int* __restrict__ cnt, uint2* __restrict__ slots,
    uint4* __restrict__ ov, int* __restrict__ ovCnt, int E)
{
    int e = blockIdx.x * 256 + threadIdx.x;
    if (e >= E) return;
    int d = ei[E + e];          // edge_index[1][e]
    int s = ei[e];              // edge_index[0][e]
    unsigned w = __float_as_uint(ea[e]);
    int pos = atomicAdd(&cnt[d], 1);
    if (pos < SLOTS) {
        slots[((size_t)d << 6) + pos] = make_uint2((unsigned)s, w);
    } else {
        int o = atomicAdd(ovCnt, 1);
        ov[o] = make_uint4((unsigned)d, (unsigned)s, w, 0u);
    }
}

// deg[n] = 1 + sum of slot weights (+overflow); dinv = rsqrt(deg)
__global__ __launch_bounds__(256) void degDinvK(
    const uint2* __restrict__ slots, const int* __restrict__ cnt,
    const uint4* __restrict__ ov, const int* __restrict__ ovCnt,
    float* __restrict__ dinv, int n)
{
    int node = blockIdx.x * 4 + (threadIdx.x >> 6);
    int lane = threadIdx.x & 63;
    if (node >= n) return;
    int c = min(cnt[node], SLOTS);
    float w = 0.f;
    if (lane < c) w = __uint_as_float(slots[((size_t)node << 6) + lane].y);
    for (int off = 1; off < 64; off <<= 1) w += __shfl_xor(w, off);
    int no = *ovCnt;
    for (int k = 0; k < no; ++k) {
        uint4 o = ov[k];
        if ((int)o.x == node) w += __uint_as_float(o.z);
    }
    if (lane == 0) dinv[node] = rsqrtf(fmaxf(1.f + w, 1e-12f));
}

// ---------------- weight convert: W[i][o] fp32 -> WT[o*136+i] bf16 (padded) ----------------

__global__ void convertWK(const float* __restrict__ W, bf16_t* __restrict__ WT) {
    int flat = blockIdx.x * 256 + threadIdx.x;   // 0..16383
    int i = flat >> 7, o = flat & 127;
    WT[o * 136 + i] = (bf16_t)W[flat];
}

// ---------------- GEMM: out[r][j] = epilogue( sum_k A[r][k]*W[k][j] ), bf16 out ----------------
// MODE 0: BN(acc + colBias) then ReLU   (input preprocess, A fp32)
// MODE 1: acc * dinv[row]               (pre-scaled conv message, A bf16)
// MODE 2: acc + colBias                 (classifier linear 1, A bf16)

template <int MODE, typename AT>
__global__ __launch_bounds__(256) void gemm128K(
    const AT* __restrict__ A, const bf16_t* __restrict__ WT,
    bf16_t* __restrict__ out,
    const float* __restrict__ colBias,
    const float* __restrict__ bnMean, const float* __restrict__ bnVar,
    const float* __restrict__ bnG, const float* __restrict__ bnB,
    const float* __restrict__ dinv, int nrows)
{
    __shared__ __align__(16) bf16_t As[64 * 136];
    __shared__ __align__(16) bf16_t Bs[128 * 136];
    int tid = threadIdx.x;
    int rb = blockIdx.x * 64;

    // stage WT (already padded, 128*136 bf16) straight into LDS
    {
        const uint4* src = (const uint4*)WT;
        uint4* dst = (uint4*)Bs;
        for (int i = tid; i < (128 * 136 * 2) / 16; i += 256) dst[i] = src[i];
    }
    // stage A tile (64 rows x 128 cols -> bf16, padded stride 136)
    if constexpr (sizeof(AT) == 4) {
        for (int it = 0; it < 8; ++it) {
            int flat = it * 1024 + tid * 4;
            int r = flat >> 7, c = flat & 127;
            int row = rb + r;
            float4 v;
            if (row < nrows) v = ((const float4*)A)[(size_t)row * 32 + (c >> 2)];
            else             v = make_float4(0.f, 0.f, 0.f, 0.f);
            bf16x4 w4;
            w4.x = (bf16_t)v.x; w4.y = (bf16_t)v.y; w4.z = (bf16_t)v.z; w4.w = (bf16_t)v.w;
            *(bf16x4*)&As[r * 136 + c] = w4;
        }
    } else {
        for (int it = 0; it < 4; ++it) {
            int flat = it * 2048 + tid * 8;
            int r = flat >> 7, c = flat & 127;
            int row = rb + r;
            bf16x8 v = (bf16x8)(bf16_t)0.f;
            if (row < nrows) v = ((const bf16x8*)A)[(size_t)row * 16 + (c >> 3)];
            *(bf16x8*)&As[r * 136 + c] = v;
        }
    }
    __syncthreads();

    int lane = tid & 63;
    int wid = tid >> 6;
    int m = lane & 15, q = lane >> 4;

    f32x4 acc[8];
#pragma unroll
    for (int c = 0; c < 8; ++c) acc[c] = (f32x4){0.f, 0.f, 0.f, 0.f};

    const bf16_t* aRow = &As[(wid * 16 + m) * 136 + q * 8];
#pragma unroll
    for (int kk = 0; kk < 4; ++kk) {
        bf16x8 af = *(const bf16x8*)(aRow + kk * 32);
#pragma unroll
        for (int c = 0; c < 8; ++c) {
            bf16x8 bfr = *(const bf16x8*)&Bs[(c * 16 + m) * 136 + q * 8 + kk * 32];
            acc[c] = __builtin_amdgcn_mfma_f32_16x16x32_bf16(af, bfr, acc[c], 0, 0, 0);
        }
    }

    int r0 = rb + wid * 16 + q * 4;
    float dv[4];
    if (MODE == 1) {
#pragma unroll
        for (int i = 0; i < 4; ++i) dv[i] = (r0 + i < nrows) ? dinv[r0 + i] : 0.f;
    }
#pragma unroll
    for (int c = 0; c < 8; ++c) {
        int j = c * 16 + m;
        float cb = 0.f, scale = 1.f, shift = 0.f;
        if (MODE == 0) {
            cb = colBias[j];
            float rs = rsqrtf(bnVar[j] + EPS_BN);
            scale = bnG[j] * rs;
            shift = bnB[j] - bnMean[j] * scale;
        } else if (MODE == 2) {
            cb = colBias[j];
        }
#pragma unroll
        for (int i = 0; i < 4; ++i) {
            int r = r0 + i;
            if (r < nrows) {
                float v = acc[c][i];
                if (MODE == 0) { v = (v + cb) * scale + shift; v = fmaxf(v, 0.f); }
                else if (MODE == 1) { v = v * dv[i]; }
                else { v = v + cb; }
                out[(size_t)r * 128 + j] = (bf16_t)v;
            }
        }
    }
}

// ---------------- aggregation: out[d] = act(dinv[d]*(ts[d] + sum w*ts[src]) + b (+res)) ----------------

template <int RELU, int RES>
__global__ __launch_bounds__(256) void aggK(
    const bf16_t* __restrict__ ts, const uint2* __restrict__ slots,
    const int* __restrict__ cnt, const float* __restrict__ dinv,
    const float* __restrict__ bias, const bf16_t* __restrict__ residual,
    bf16_t* __restrict__ out,
    const uint4* __restrict__ ov, const int* __restrict__ ovCnt, int n)
{
    int node = blockIdx.x * 4 + (threadIdx.x >> 6);
    int lane = threadIdx.x & 63;
    if (node >= n) return;
    const bf16x2* tsv = (const bf16x2*)ts;
    bf16x2 sv = tsv[((size_t)node << 6) + lane];
    float2 acc = make_float2((float)sv.x, (float)sv.y);   // self-loop term
    int c = min(cnt[node], SLOTS);
    const uint2* row = slots + ((size_t)node << 6);
    int j = 0;
    for (; j + 1 < c; j += 2) {
        uint2 e0 = row[j];
        uint2 e1 = row[j + 1];
        bf16x2 v0 = tsv[((size_t)e0.x << 6) + lane];
        bf16x2 v1 = tsv[((size_t)e1.x << 6) + lane];
        float w0 = __uint_as_float(e0.y), w1 = __uint_as_float(e1.y);
        acc.x += w0 * (float)v0.x + w1 * (float)v1.x;
        acc.y += w0 * (float)v0.y + w1 * (float)v1.y;
    }
    if (j < c) {
        uint2 e0 = row[j];
        bf16x2 v0 = tsv[((size_t)e0.x << 6) + lane];
        float w0 = __uint_as_float(e0.y);
        acc.x += w0 * (float)v0.x;
        acc.y += w0 * (float)v0.y;
    }
    int no = *ovCnt;
    for (int k = 0; k < no; ++k) {
        uint4 o = ov[k];
        if ((int)o.x == node) {
            bf16x2 v = tsv[((size_t)o.y << 6) + lane];
            float w = __uint_as_float(o.z);
            acc.x += w * (float)v.x;
            acc.y += w * (float)v.y;
        }
    }
    float di = dinv[node];
    float2 bb = ((const float2*)bias)[lane];
    float rx = acc.x * di + bb.x;
    float ry = acc.y * di + bb.y;
    if (RES) {
        bf16x2 rr = ((const bf16x2*)residual)[((size_t)node << 6) + lane];
        rx += (float)rr.x; ry += (float)rr.y;
    }
    if (RELU) { rx = fmaxf(rx, 0.f); ry = fmaxf(ry, 0.f); }
    bf16x2 o2; o2.x = (bf16_t)rx; o2.y = (bf16_t)ry;
    ((bf16x2*)out)[((size_t)node << 6) + lane] = o2;
}

// ---------------- final: LayerNorm -> ReLU -> Linear(128->3) ----------------

__global__ __launch_bounds__(256) void finalK(
    const bf16_t* __restrict__ Z, const float* __restrict__ g,
    const float* __restrict__ b, const float* __restrict__ Wc2,
    const float* __restrict__ bc2, float* __restrict__ out, int n)
{
    int node = blockIdx.x * 4 + (threadIdx.x >> 6);
    int lane = threadIdx.x & 63;
    if (node >= n) return;
    bf16x2 z2 = ((const bf16x2*)Z)[((size_t)node << 6) + lane];
    float zx0 = (float)z2.x, zy0 = (float)z2.y;
    float s1 = zx0 + zy0;
    float s2 = zx0 * zx0 + zy0 * zy0;
    for (int off = 1; off < 64; off <<= 1) {
        s1 += __shfl_xor(s1, off);
        s2 += __shfl_xor(s2, off);
    }
    float mu = s1 * (1.f / 128.f);
    float var = s2 * (1.f / 128.f) - mu * mu;
    float rstd = rsqrtf(var + EPS_LN);
    float zx = fmaxf((zx0 - mu) * rstd * g[2 * lane] + b[2 * lane], 0.f);
    float zy = fmaxf((zy0 - mu) * rstd * g[2 * lane + 1] + b[2 * lane + 1], 0.f);
    float p0 = zx * Wc2[(2 * lane) * 3 + 0] + zy * Wc2[(2 * lane + 1) * 3 + 0];
    float p1 = zx * Wc2[(2 * lane) * 3 + 1] + zy * Wc2[(2 * lane + 1) * 3 + 1];
    float p2 = zx * Wc2[(2 * lane) * 3 + 2] + zy * Wc2[(2 * lane + 1) * 3 + 2];
    for (int off = 1; off < 64; off <<= 1) {
        p0 += __shfl_xor(p0, off);
        p1 += __shfl_xor(p1, off);
        p2 += __shfl_xor(p2, off);
    }
    if (lane == 0) {
        out[(size_t)node * 3 + 0] = p0 + bc2[0];
        out[(size_t)node * 3 + 1] = p1 + bc2[1];
        out[(size_t)node * 3 + 2] = p2 + bc2[2];
    }
}

// ---------------- launch ----------------

extern "C" void kernel_launch(void* const* d_in, const int* in_sizes, int n_in,
                              void* d_out, int out_size, void* d_ws, size_t ws_size,
                              hipStream_t stream) {
    const float* x      = (const float*)d_in[0];
    const int*   ei     = (const int*)d_in[1];
    const float* ea     = (const float*)d_in[2];
    const float* W_pre  = (const float*)d_in[3];
    const float* b_pre  = (const float*)d_in[4];
    const float* bn_g   = (const float*)d_in[5];
    const float* bn_b   = (const float*)d_in[6];
    const float* bn_m   = (const float*)d_in[7];
    const float* bn_v   = (const float*)d_in[8];
    const float* W1     = (const float*)d_in[9];
    const float* b1     = (const float*)d_in[10];
    const float* W2     = (const float*)d_in[11];
    const float* b2     = (const float*)d_in[12];
    const float* Wc1    = (const float*)d_in[13];
    const float* bc1    = (const float*)d_in[14];
    const float* ln_g   = (const float*)d_in[15];
    const float* ln_b   = (const float*)d_in[16];
    const float* Wc2    = (const float*)d_in[17];
    const float* bc2    = (const float*)d_in[18];
    float* outp = (float*)d_out;

    const int N = in_sizes[0] / 128;
    const int E = in_sizes[2];

    char* p = (char*)d_ws;
    auto alloc = [&](size_t bytes) -> void* {
        void* r = (void*)p;
        p += (bytes + 255) & ~(size_t)255;
        return r;
    };
    bf16_t* h0    = (bf16_t*)alloc((size_t)N * 128 * 2);
    bf16_t* bufA  = (bf16_t*)alloc((size_t)N * 128 * 2);
    bf16_t* bufB  = (bf16_t*)alloc((size_t)N * 128 * 2);
    float*  dinv  = (float*)alloc((size_t)N * 4);
    int*    cnt   = (int*)alloc((size_t)N * 4);
    int*    ovCnt = (int*)alloc(256);
    uint4*  ov    = (uint4*)alloc((size_t)4096 * 16);
    uint2*  slots = (uint2*)alloc((size_t)N * SLOTS * 8);
    bf16_t* WT    = (bf16_t*)alloc((size_t)4 * 128 * 136 * 2);

    bf16_t* WT_pre = WT + 0 * 128 * 136;
    bf16_t* WT_1   = WT + 1 * 128 * 136;
    bf16_t* WT_2   = WT + 2 * 128 * 136;
    bf16_t* WT_c1  = WT + 3 * 128 * 136;

    int gN = (N + 255) / 256;
    int gE = (E + 255) / 256;
    int gG = (N + 63) / 64;
    int gW = (N + 3) / 4;

    // adjacency build (fixed slots) + dinv
    initK<<<gN, 256, 0, stream>>>(cnt, ovCnt, N);
    fillSlotsK<<<gE, 256, 0, stream>>>(ei, ea, cnt, slots, ov, ovCnt, E);
    degDinvK<<<gW, 256, 0, stream>>>(slots, cnt, ov, ovCnt, dinv, N);

    // weights -> bf16 transposed, padded
    convertWK<<<64, 256, 0, stream>>>(W_pre, WT_pre);
    convertWK<<<64, 256, 0, stream>>>(W1, WT_1);
    convertWK<<<64, 256, 0, stream>>>(W2, WT_2);
    convertWK<<<64, 256, 0, stream>>>(Wc1, WT_c1);

    // h0 = relu(bn(x@W_pre + b_pre))
    gemm128K<0, float><<<gG, 256, 0, stream>>>(x, WT_pre, h0, b_pre, bn_m, bn_v, bn_g, bn_b, nullptr, N);
    // conv1: ts1 = dinv * (h0@W1); h1 = relu(dinv*(ts1[d] + sum) + b1)
    gemm128K<1, bf16_t><<<gG, 256, 0, stream>>>(h0, WT_1, bufA, nullptr, nullptr, nullptr, nullptr, nullptr, dinv, N);
    aggK<1, 0><<<gW, 256, 0, stream>>>(bufA, slots, cnt, dinv, b1, nullptr, bufB, ov, ovCnt, N);
    // conv2: ts2 = dinv * (h1@W2); h = dinv*(...) + b2 + h0
    gemm128K<1, bf16_t><<<gG, 256, 0, stream>>>(bufB, WT_2, bufA, nullptr, nullptr, nullptr, nullptr, nullptr, dinv, N);
    aggK<0, 1><<<gW, 256, 0, stream>>>(bufA, slots, cnt, dinv, b2, h0, bufB, ov, ovCnt, N);
    // z = h@Wc1 + bc1
    gemm128K<2, bf16_t><<<gG, 256, 0, stream>>>(bufB, WT_c1, bufA, bc1, nullptr, nullptr, nullptr, nullptr, nullptr, N);
    // out = relu(LN(z)) @ Wc2 + bc2
    finalK<<<gW, 256, 0, stream>>>(bufA, ln_g, ln_b, Wc2, bc2, outp, N);
}

// Round 3
// 534.713 us; speedup vs baseline: 1.5422x; 1.1300x over previous
//
#include <hip/hip_runtime.h>
#include <hip/hip_bf16.h>

typedef __bf16 bf16_t;
typedef bf16_t bf16x8 __attribute__((ext_vector_type(8)));
typedef bf16_t bf16x4 __attribute__((ext_vector_type(4)));
typedef bf16_t bf16x2 __attribute__((ext_vector_type(2)));
typedef float f32x4 __attribute__((ext_vector_type(4)));

#define EPS_BN 1e-5f
#define EPS_LN 1e-5f
#define SLOTS 64
#define NPASS 8
#define WSCALE 32767.f
#define WINV (1.f / 32767.f)

// ---------------- weight convert: 4x W[i][o] fp32 -> WT[o*136+i] bf16 (padded) ----------------

__global__ void convertAllK(const float* __restrict__ W0, const float* __restrict__ W1,
                            const float* __restrict__ W2, const float* __restrict__ W3,
                            bf16_t* __restrict__ WT) {
    int flat = blockIdx.x * 256 + threadIdx.x;   // 0..65535
    int which = flat >> 14, r = flat & 16383;
    const float* W = (which == 0) ? W0 : (which == 1) ? W1 : (which == 2) ? W2 : W3;
    int i = r >> 7, o = r & 127;
    WT[which * 128 * 136 + o * 136 + i] = (bf16_t)W[r];
}

// ---------------- adjacency fill, one dst-range pass (L2-resident scatter) ----------------
// slot entry: (src << 15) | round(w * 32767), w in [0,1)

__global__ __launch_bounds__(256) void fillPassK(
    const int* __restrict__ ei, const float* __restrict__ ea,
    int* __restrict__ cnt, unsigned* __restrict__ slots,
    uint2* __restrict__ ov, int* __restrict__ ovCnt, int E, int lo, int hi)
{
    int e = blockIdx.x * 256 + threadIdx.x;
    if (e >= E) return;
    int d = ei[E + e];          // edge_index[1][e]
    if (d < lo || d >= hi) return;
    int s = ei[e];              // edge_index[0][e]
    unsigned wq = __float2uint_rn(ea[e] * WSCALE);
    unsigned pk = ((unsigned)s << 15) | wq;
    int pos = atomicAdd(&cnt[d], 1);
    if (pos < SLOTS) {
        slots[((size_t)d << 6) + pos] = pk;
    } else {
        int o = atomicAdd(ovCnt, 1);
        ov[o] = make_uint2((unsigned)d, pk);
    }
}

// deg[n] = 1 + sum of slot weights (+overflow); dinv = rsqrt(deg)
__global__ __launch_bounds__(256) void degDinvK(
    const unsigned* __restrict__ slots, const int* __restrict__ cnt,
    const uint2* __restrict__ ov, const int* __restrict__ ovCnt,
    float* __restrict__ dinv, int n)
{
    int node = blockIdx.x * 4 + (threadIdx.x >> 6);
    int lane = threadIdx.x & 63;
    if (node >= n) return;
    int c = min(cnt[node], SLOTS);
    float w = 0.f;
    if (lane < c) w = (float)(slots[((size_t)node << 6) + lane] & 32767u) * WINV;
    for (int off = 1; off < 64; off <<= 1) w += __shfl_xor(w, off);
    int no = *ovCnt;
    for (int k = 0; k < no; ++k) {
        uint2 o = ov[k];
        if ((int)o.x == node) w += (float)(o.y & 32767u) * WINV;
    }
    if (lane == 0) dinv[node] = rsqrtf(fmaxf(1.f + w, 1e-12f));
}

// ---------------- GEMM: out[r][j] = epilogue( sum_k A[r][k]*W[k][j] ), bf16 out ----------------
// MODE 0: BN(acc + colBias) then ReLU   (input preprocess, A fp32)
// MODE 1: acc * dinv[row]               (pre-scaled conv message, A bf16)
// MODE 2: acc + colBias                 (classifier linear 1, A bf16)

template <int MODE, typename AT>
__global__ __launch_bounds__(256) void gemm128K(
    const AT* __restrict__ A, const bf16_t* __restrict__ WT,
    bf16_t* __restrict__ out,
    const float* __restrict__ colBias,
    const float* __restrict__ bnMean, const float* __restrict__ bnVar,
    const float* __restrict__ bnG, const float* __restrict__ bnB,
    const float* __restrict__ dinv, int nrows)
{
    __shared__ __align__(16) bf16_t As[64 * 136];
    __shared__ __align__(16) bf16_t Bs[128 * 136];
    int tid = threadIdx.x;
    int rb = blockIdx.x * 64;

    // stage WT (already padded, 128*136 bf16) straight into LDS
    {
        const uint4* src = (const uint4*)WT;
        uint4* dst = (uint4*)Bs;
        for (int i = tid; i < (128 * 136 * 2) / 16; i += 256) dst[i] = src[i];
    }
    // stage A tile (64 rows x 128 cols -> bf16, padded stride 136)
    if constexpr (sizeof(AT) == 4) {
        for (int it = 0; it < 8; ++it) {
            int flat = it * 1024 + tid * 4;
            int r = flat >> 7, c = flat & 127;
            int row = rb + r;
            float4 v;
            if (row < nrows) v = ((const float4*)A)[(size_t)row * 32 + (c >> 2)];
            else             v = make_float4(0.f, 0.f, 0.f, 0.f);
            bf16x4 w4;
            w4.x = (bf16_t)v.x; w4.y = (bf16_t)v.y; w4.z = (bf16_t)v.z; w4.w = (bf16_t)v.w;
            *(bf16x4*)&As[r * 136 + c] = w4;
        }
    } else {
        for (int it = 0; it < 4; ++it) {
            int flat = it * 2048 + tid * 8;
            int r = flat >> 7, c = flat & 127;
            int row = rb + r;
            bf16x8 v = (bf16x8)(bf16_t)0.f;
            if (row < nrows) v = ((const bf16x8*)A)[(size_t)row * 16 + (c >> 3)];
            *(bf16x8*)&As[r * 136 + c] = v;
        }
    }
    __syncthreads();

    int lane = tid & 63;
    int wid = tid >> 6;
    int m = lane & 15, q = lane >> 4;

    f32x4 acc[8];
#pragma unroll
    for (int c = 0; c < 8; ++c) acc[c] = (f32x4){0.f, 0.f, 0.f, 0.f};

    const bf16_t* aRow = &As[(wid * 16 + m) * 136 + q * 8];
#pragma unroll
    for (int kk = 0; kk < 4; ++kk) {
        bf16x8 af = *(const bf16x8*)(aRow + kk * 32);
#pragma unroll
        for (int c = 0; c < 8; ++c) {
            bf16x8 bfr = *(const bf16x8*)&Bs[(c * 16 + m) * 136 + q * 8 + kk * 32];
            acc[c] = __builtin_amdgcn_mfma_f32_16x16x32_bf16(af, bfr, acc[c], 0, 0, 0);
        }
    }

    int r0 = rb + wid * 16 + q * 4;
    float dv[4];
    if (MODE == 1) {
#pragma unroll
        for (int i = 0; i < 4; ++i) dv[i] = (r0 + i < nrows) ? dinv[r0 + i] : 0.f;
    }
#pragma unroll
    for (int c = 0; c < 8; ++c) {
        int j = c * 16 + m;
        float cb = 0.f, scale = 1.f, shift = 0.f;
        if (MODE == 0) {
            cb = colBias[j];
            float rs = rsqrtf(bnVar[j] + EPS_BN);
            scale = bnG[j] * rs;
            shift = bnB[j] - bnMean[j] * scale;
        } else if (MODE == 2) {
            cb = colBias[j];
        }
#pragma unroll
        for (int i = 0; i < 4; ++i) {
            int r = r0 + i;
            if (r < nrows) {
                float v = acc[c][i];
                if (MODE == 0) { v = (v + cb) * scale + shift; v = fmaxf(v, 0.f); }
                else if (MODE == 1) { v = v * dv[i]; }
                else { v = v + cb; }
                out[(size_t)r * 128 + j] = (bf16_t)v;
            }
        }
    }
}

// ---------------- aggregation: out[d] = act(dinv[d]*(ts[d] + sum w*ts[src]) + b (+res)) ----------------

template <int RELU, int RES>
__global__ __launch_bounds__(256) void aggK(
    const bf16_t* __restrict__ ts, const unsigned* __restrict__ slots,
    const int* __restrict__ cnt, const float* __restrict__ dinv,
    const float* __restrict__ bias, const bf16_t* __restrict__ residual,
    bf16_t* __restrict__ out,
    const uint2* __restrict__ ov, const int* __restrict__ ovCnt, int n)
{
    int node = blockIdx.x * 4 + (threadIdx.x >> 6);
    int lane = threadIdx.x & 63;
    if (node >= n) return;
    const bf16x2* tsv = (const bf16x2*)ts;
    bf16x2 sv = tsv[((size_t)node << 6) + lane];
    float2 acc = make_float2((float)sv.x, (float)sv.y);   // self-loop term
    int c = min(cnt[node], SLOTS);
    // one coalesced load of the whole row; broadcast via shfl
    unsigned my = (lane < c) ? slots[((size_t)node << 6) + lane] : 0u;
    int j = 0;
    for (; j + 3 < c; j += 4) {
        unsigned p0 = __shfl(my, j), p1 = __shfl(my, j + 1);
        unsigned p2 = __shfl(my, j + 2), p3 = __shfl(my, j + 3);
        bf16x2 v0 = tsv[((size_t)(p0 >> 15) << 6) + lane];
        bf16x2 v1 = tsv[((size_t)(p1 >> 15) << 6) + lane];
        bf16x2 v2 = tsv[((size_t)(p2 >> 15) << 6) + lane];
        bf16x2 v3 = tsv[((size_t)(p3 >> 15) << 6) + lane];
        float w0 = (float)(p0 & 32767u) * WINV, w1 = (float)(p1 & 32767u) * WINV;
        float w2 = (float)(p2 & 32767u) * WINV, w3 = (float)(p3 & 32767u) * WINV;
        acc.x += w0 * (float)v0.x + w1 * (float)v1.x + w2 * (float)v2.x + w3 * (float)v3.x;
        acc.y += w0 * (float)v0.y + w1 * (float)v1.y + w2 * (float)v2.y + w3 * (float)v3.y;
    }
    for (; j < c; ++j) {
        unsigned p0 = __shfl(my, j);
        bf16x2 v0 = tsv[((size_t)(p0 >> 15) << 6) + lane];
        float w0 = (float)(p0 & 32767u) * WINV;
        acc.x += w0 * (float)v0.x;
        acc.y += w0 * (float)v0.y;
    }
    int no = *ovCnt;
    for (int k = 0; k < no; ++k) {
        uint2 o = ov[k];
        if ((int)o.x == node) {
            bf16x2 v = tsv[((size_t)(o.y >> 15) << 6) + lane];
            float w = (float)(o.y & 32767u) * WINV;
            acc.x += w * (float)v.x;
            acc.y += w * (float)v.y;
        }
    }
    float di = dinv[node];
    float2 bb = ((const float2*)bias)[lane];
    float rx = acc.x * di + bb.x;
    float ry = acc.y * di + bb.y;
    if (RES) {
        bf16x2 rr = ((const bf16x2*)residual)[((size_t)node << 6) + lane];
        rx += (float)rr.x; ry += (float)rr.y;
    }
    if (RELU) { rx = fmaxf(rx, 0.f); ry = fmaxf(ry, 0.f); }
    bf16x2 o2; o2.x = (bf16_t)rx; o2.y = (bf16_t)ry;
    ((bf16x2*)out)[((size_t)node << 6) + lane] = o2;
}

// ---------------- final: LayerNorm -> ReLU -> Linear(128->3) ----------------

__global__ __launch_bounds__(256) void finalK(
    const bf16_t* __restrict__ Z, const float* __restrict__ g,
    const float* __restrict__ b, const float* __restrict__ Wc2,
    const float* __restrict__ bc2, float* __restrict__ out, int n)
{
    int node = blockIdx.x * 4 + (threadIdx.x >> 6);
    int lane = threadIdx.x & 63;
    if (node >= n) return;
    bf16x2 z2 = ((const bf16x2*)Z)[((size_t)node << 6) + lane];
    float zx0 = (float)z2.x, zy0 = (float)z2.y;
    float s1 = zx0 + zy0;
    float s2 = zx0 * zx0 + zy0 * zy0;
    for (int off = 1; off < 64; off <<= 1) {
        s1 += __shfl_xor(s1, off);
        s2 += __shfl_xor(s2, off);
    }
    float mu = s1 * (1.f / 128.f);
    float var = s2 * (1.f / 128.f) - mu * mu;
    float rstd = rsqrtf(var + EPS_LN);
    float zx = fmaxf((zx0 - mu) * rstd * g[2 * lane] + b[2 * lane], 0.f);
    float zy = fmaxf((zy0 - mu) * rstd * g[2 * lane + 1] + b[2 * lane + 1], 0.f);
    float p0 = zx * Wc2[(2 * lane) * 3 + 0] + zy * Wc2[(2 * lane + 1) * 3 + 0];
    float p1 = zx * Wc2[(2 * lane) * 3 + 1] + zy * Wc2[(2 * lane + 1) * 3 + 1];
    float p2 = zx * Wc2[(2 * lane) * 3 + 2] + zy * Wc2[(2 * lane + 1) * 3 + 2];
    for (int off = 1; off < 64; off <<= 1) {
        p0 += __shfl_xor(p0, off);
        p1 += __shfl_xor(p1, off);
        p2 += __shfl_xor(p2, off);
    }
    if (lane == 0) {
        out[(size_t)node * 3 + 0] = p0 + bc2[0];
        out[(size_t)node * 3 + 1] = p1 + bc2[1];
        out[(size_t)node * 3 + 2] = p2 + bc2[2];
    }
}

// ---------------- launch ----------------

extern "C" void kernel_launch(void* const* d_in, const int* in_sizes, int n_in,
                              void* d_out, int out_size, void* d_ws, size_t ws_size,
                              hipStream_t stream) {
    const float* x      = (const float*)d_in[0];
    const int*   ei     = (const int*)d_in[1];
    const float* ea     = (const float*)d_in[2];
    const float* W_pre  = (const float*)d_in[3];
    const float* b_pre  = (const float*)d_in[4];
    const float* bn_g   = (const float*)d_in[5];
    const float* bn_b   = (const float*)d_in[6];
    const float* bn_m   = (const float*)d_in[7];
    const float* bn_v   = (const float*)d_in[8];
    const float* W1     = (const float*)d_in[9];
    const float* b1     = (const float*)d_in[10];
    const float* W2     = (const float*)d_in[11];
    const float* b2     = (const float*)d_in[12];
    const float* Wc1    = (const float*)d_in[13];
    const float* bc1    = (const float*)d_in[14];
    const float* ln_g   = (const float*)d_in[15];
    const float* ln_b   = (const float*)d_in[16];
    const float* Wc2    = (const float*)d_in[17];
    const float* bc2    = (const float*)d_in[18];
    float* outp = (float*)d_out;

    const int N = in_sizes[0] / 128;
    const int E = in_sizes[2];

    char* p = (char*)d_ws;
    auto alloc = [&](size_t bytes) -> void* {
        void* r = (void*)p;
        p += (bytes + 255) & ~(size_t)255;
        return r;
    };
    bf16_t*   h0    = (bf16_t*)alloc((size_t)N * 128 * 2);
    bf16_t*   bufA  = (bf16_t*)alloc((size_t)N * 128 * 2);
    bf16_t*   bufB  = (bf16_t*)alloc((size_t)N * 128 * 2);
    float*    dinv  = (float*)alloc((size_t)N * 4);
    int*      cnt   = (int*)alloc((size_t)N * 4);
    int*      ovCnt = (int*)alloc(256);
    uint2*    ov    = (uint2*)alloc((size_t)4096 * 8);
    unsigned* slots = (unsigned*)alloc((size_t)N * SLOTS * 4);
    bf16_t*   WT    = (bf16_t*)alloc((size_t)4 * 128 * 136 * 2);

    bf16_t* WT_pre = WT + 0 * 128 * 136;
    bf16_t* WT_1   = WT + 1 * 128 * 136;
    bf16_t* WT_2   = WT + 2 * 128 * 136;
    bf16_t* WT_c1  = WT + 3 * 128 * 136;

    int gE = (E + 255) / 256;
    int gG = (N + 63) / 64;
    int gW = (N + 3) / 4;

    // zero cnt + ovCnt
    hipMemsetAsync(cnt, 0, (size_t)N * 4, stream);
    hipMemsetAsync(ovCnt, 0, 4, stream);

    // weights -> bf16 transposed, padded (single launch)
    convertAllK<<<256, 256, 0, stream>>>(W_pre, W1, W2, Wc1, WT);

    // adjacency fill: NPASS dst-range passes so the scatter region is L2-resident
    int range = (N + NPASS - 1) / NPASS;
    for (int ps = 0; ps < NPASS; ++ps) {
        int lo = ps * range;
        int hi = min(N, lo + range);
        fillPassK<<<gE, 256, 0, stream>>>(ei, ea, cnt, slots, ov, ovCnt, E, lo, hi);
    }
    degDinvK<<<gW, 256, 0, stream>>>(slots, cnt, ov, ovCnt, dinv, N);

    // h0 = relu(bn(x@W_pre + b_pre))
    gemm128K<0, float><<<gG, 256, 0, stream>>>(x, WT_pre, h0, b_pre, bn_m, bn_v, bn_g, bn_b, nullptr, N);
    // conv1: ts1 = dinv * (h0@W1); h1 = relu(dinv*(ts1[d] + sum) + b1)
    gemm128K<1, bf16_t><<<gG, 256, 0, stream>>>(h0, WT_1, bufA, nullptr, nullptr, nullptr, nullptr, nullptr, dinv, N);
    aggK<1, 0><<<gW, 256, 0, stream>>>(bufA, slots, cnt, dinv, b1, nullptr, bufB, ov, ovCnt, N);
    // conv2: ts2 = dinv * (h1@W2); h = dinv*(...) + b2 + h0
    gemm128K<1, bf16_t><<<gG, 256, 0, stream>>>(bufB, WT_2, bufA, nullptr, nullptr, nullptr, nullptr, nullptr, dinv, N);
    aggK<0, 1><<<gW, 256, 0, stream>>>(bufA, slots, cnt, dinv, b2, h0, bufB, ov, ovCnt, N);
    // z = h@Wc1 + bc1
    gemm128K<2, bf16_t><<<gG, 256, 0, stream>>>(bufB, WT_c1, bufA, bc1, nullptr, nullptr, nullptr, nullptr, nullptr, N);
    // out = relu(LN(z)) @ Wc2 + bc2
    finalK<<<gW, 256, 0, stream>>>(bufA, ln_g, ln_b, Wc2, bc2, outp, N);
}